// Round 5
// baseline (73.574 us; speedup 1.0000x reference)
//
#include <hip/hip_runtime.h>

#define IMG   224
#define IMG2  (IMG*IMG)
#define KK    256
#define EE    128
#define RCOLS 144

typedef float f32x4 __attribute__((ext_vector_type(4)));
typedef short s16x8 __attribute__((ext_vector_type(8)));

__device__ __forceinline__ unsigned short f2bf(float f) {
    unsigned int u = __float_as_uint(f);
    u = (u + 0x7fffu + ((u >> 16) & 1u)) >> 16;   // RNE (inputs finite)
    return (unsigned short)u;
}
__device__ __forceinline__ float bf2f(unsigned short u) {
    return __uint_as_float((unsigned int)u << 16);
}
__device__ __forceinline__ uint2 pack4(f32x4 r) {
    unsigned int lo = (unsigned int)f2bf(r.x) | ((unsigned int)f2bf(r.y) << 16);
    unsigned int hi = (unsigned int)f2bf(r.z) | ((unsigned int)f2bf(r.w) << 16);
    return make_uint2(lo, hi);
}

// M[c][k][j] = sum_e W_dec[c][k][e]*W_enc[c][e][j], packed in MFMA A-frag order:
// APK[c][kf(16)][jb(8)][lane(64)][i(8)] = bf16(M[kf*16+(lane&15)][jb*32+8*(lane>>4)+i])
// Also v[c][k] = b_dec[c][k] + sum_e W_dec[c][k][e]*b_enc[c][e].
__global__ void pack_M(const float* __restrict__ W_enc, const float* __restrict__ W_dec,
                       const float* __restrict__ b_enc, const float* __restrict__ b_dec,
                       unsigned short* __restrict__ APK, float* __restrict__ v) {
    int k = blockIdx.x, c = blockIdx.y, j = threadIdx.x;
    const float* wd = W_dec + ((size_t)c*KK + k)*EE;
    const float* we = W_enc + (size_t)c*EE*KK + j;
    float acc = 0.f;
    #pragma unroll 8
    for (int e = 0; e < EE; ++e) acc = fmaf(wd[e], we[(size_t)e*KK], acc);
    int kf = k >> 4, kr = k & 15, jb = j >> 5, g = (j >> 3) & 3, i = j & 7;
    APK[(size_t)c*65536 + (((kf*8 + jb)*64) + g*16 + kr)*8 + i] = f2bf(acc);

    __shared__ float pv[128];
    if (j < EE) pv[j] = wd[j] * b_enc[c*EE + j];
    __syncthreads();
    for (int off = 64; off > 0; off >>= 1) {
        if (j < off) pv[j] += pv[j + off];
        __syncthreads();
    }
    if (j == 0) v[c*KK + k] = pv[0] + b_dec[c*KK + k];
}

// Block = (b, c, band, seg). band: patches 13*band..13*band+13, output cols [112*band,112*band+112).
// seg: patch-rows ny in [N0,N1], output strips [9*seg, ...]. A-frags register-resident.
__global__ __launch_bounds__(256, 2)
void patch_ae_loop(const float* __restrict__ x, const unsigned short* __restrict__ APK,
                   const float* __restrict__ v, float* __restrict__ out)
{
    // XCD swizzle: 1152 = 8 x 144; XCD j gets contiguous lids (8 (b,c) groups of 6)
    const int hid = blockIdx.x + 6*(blockIdx.y + 3*blockIdx.z);
    const int lid = (hid & 7)*144 + (hid >> 3);
    const int u   = lid % 6;
    const int rem = lid / 6;
    const int c   = rem % 3;
    const int b   = rem / 3;
    const int seg = u % 3, band = u / 3;
    const int S0 = 9*seg;
    const int N0 = seg ? 9*seg - 1 : 0;
    const int N1 = (seg == 2) ? 26 : 9*seg + 8;

    const int tid  = threadIdx.x;
    const int lane = tid & 63, wave = tid >> 6;

    __shared__ __align__(16) unsigned short ring[24*RCOLS];   // 6912 B
    __shared__ __align__(16) unsigned short recT[16][136];    // 4352 B
    __shared__ __align__(16) unsigned short recB[2][16][136]; // 8704 B
    __shared__ float vsh[256];                                // 1024 B

    // ---- A fragments: register-resident for the whole block ----
    const s16x8* APKc = (const s16x8*)(APK + (size_t)c*65536);
    s16x8 a[4][8];
    #pragma unroll
    for (int f = 0; f < 4; ++f)
        #pragma unroll
        for (int jb = 0; jb < 8; ++jb)
            a[f][jb] = APKc[(((wave*4 + f)*8 + jb) << 6) + lane];

    vsh[tid] = v[c*KK + tid];

    const float* xb = x + (size_t)(b*3 + c)*IMG2;
    const int colbase = band*104;

    // ---- prologue: stage image rows [8*N0, 8*N0+16), cols [colbase, colbase+144) ----
    #pragma unroll
    for (int k = 0; k < 3; ++k) {
        int idx = tid + k*256;
        if (idx < 16*36) {
            int rr = idx/36, c4 = idx - rr*36;
            int y  = 8*N0 + rr;
            int gc = colbase + c4*4;
            float4 xv = make_float4(0.f, 0.f, 0.f, 0.f);
            if (gc + 3 < IMG) xv = *((const float4*)(xb + (size_t)y*IMG + gc));
            f32x4 xr = {xv.x, xv.y, xv.z, xv.w};
            *((uint2*)&ring[(y % 24)*RCOLS + c4*4]) = pack4(xr);
        }
    }
    __syncthreads();

    const int g = lane >> 4, lr = lane & 15;
    const int bcolb = lr*16 + (g & 1)*16;   // byte offset within ring row
    const int jyoff = g >> 1;
    const int ra = tid/36,        ca = tid - (tid/36)*36;
    const int rb = (tid+256)/36,  cb = (tid+256) - ((tid+256)/36)*36;

    int base24 = (8*N0) % 24;

    #pragma unroll 1
    for (int ny = N0; ny <= N1; ++ny) {
        // --- prefetch next 8 rows into registers (issued before MFMA; T14) ---
        float4 pa = make_float4(0,0,0,0), pb = make_float4(0,0,0,0);
        if (ny < N1) {
            int gc = colbase + ca*4;
            if (gc + 3 < IMG) pa = *((const float4*)(xb + (size_t)(8*ny+16+ra)*IMG + gc));
            if (tid < 32) {
                int gc2 = colbase + cb*4;
                if (gc2 + 3 < IMG) pb = *((const float4*)(xb + (size_t)(8*ny+16+rb)*IMG + gc2));
            }
        }

        // --- MFMA: 8 jb, A from regs, B one b128 from ring ---
        f32x4 acc[4];
        #pragma unroll
        for (int f = 0; f < 4; ++f) acc[f] = (f32x4){0.f, 0.f, 0.f, 0.f};

        __builtin_amdgcn_s_setprio(1);
        #pragma unroll
        for (int jb = 0; jb < 8; ++jb) {
            int jy = 2*jb + jyoff;
            int slot = base24 + jy; if (slot >= 24) slot -= 24;
            s16x8 bf = *((const s16x8*)((const char*)ring + slot*(RCOLS*2) + bcolb));
            #pragma unroll
            for (int f = 0; f < 4; ++f)
                acc[f] = __builtin_amdgcn_mfma_f32_16x16x32_bf16(a[f][jb], bf, acc[f], 0, 0, 0);
        }
        __builtin_amdgcn_s_setprio(0);

        // --- bias + rec store (D: col=patch=lane&15, row k=(lane>>4)*4+reg) ---
        const int cur = ny & 1;
        #pragma unroll
        for (int f = 0; f < 4; ++f) {
            int k = wave*64 + f*16 + g*4;
            f32x4 bias = *((const f32x4*)&vsh[k]);
            uint2 pk = pack4(acc[f] + bias);
            if (wave < 2) *((uint2*)&recT[lr][k])            = pk;
            else          *((uint2*)&recB[cur][lr][k - 128]) = pk;
        }

        // --- write prefetched rows into ring (slots disjoint from this ny's reads) ---
        if (ny < N1) {
            int sb = base24 + 16; if (sb >= 24) sb -= 24;
            {
                int slot = sb + ra; if (slot >= 24) slot -= 24;
                f32x4 xr = {pa.x, pa.y, pa.z, pa.w};
                *((uint2*)&ring[slot*RCOLS + ca*4]) = pack4(xr);
            }
            if (tid < 32) {
                int slot = sb + rb; if (slot >= 24) slot -= 24;
                f32x4 xr = {pb.x, pb.y, pb.z, pb.w};
                *((uint2*)&ring[slot*RCOLS + cb*4]) = pack4(xr);
            }
        }
        __syncthreads();

        // --- epilogue: output strip ny (top of ny + bottom of ny-1) ---
        if (ny >= S0 && tid < 224) {
            int xl = tid % 112, rh = tid / 112;
            int xc = band*112 + xl;
            int p1 = xc >> 3;
            int pp1 = p1 - 13*band;
            int dx1 = xc & 7;
            int v1 = (pp1 <= 13);
            int v0 = (p1 >= 1);
            int pp0 = pp1 - 1;
            int hB = (ny > 0);
            int prev = (ny + 1) & 1;
            int shift = (v0 & v1) + hB;
            float inv = __int_as_float(0x3f800000 - (shift << 23)); // exact 1/2^shift
            float* op = out + (size_t)(b*3 + c)*IMG2 + (size_t)(8*ny)*IMG + xc;
            #pragma unroll
            for (int q = 0; q < 4; ++q) {
                int r = rh*4 + q;
                int kl1 = r*16 + dx1, kl0 = kl1 + 8;
                float s = 0.f;
                if (v1) { s += bf2f(recT[pp1][kl1]); if (hB) s += bf2f(recB[prev][pp1][kl1]); }
                if (v0) { s += bf2f(recT[pp0][kl0]); if (hB) s += bf2f(recB[prev][pp0][kl0]); }
                op[(size_t)r*IMG] = s * inv;
            }
        }
        __syncthreads();

        base24 += 8; if (base24 >= 24) base24 -= 24;
    }

    // ---- strip 27 (bottom halves of ny=26) — seg 2 only ----
    if (seg == 2 && tid < 224) {
        int xl = tid % 112, rh = tid / 112;
        int xc = band*112 + xl;
        int p1 = xc >> 3;
        int pp1 = p1 - 13*band;
        int dx1 = xc & 7;
        int v1 = (pp1 <= 13);
        int v0 = (p1 >= 1);
        int pp0 = pp1 - 1;
        int shift = (v0 & v1);
        float inv = __int_as_float(0x3f800000 - (shift << 23));
        float* op = out + (size_t)(b*3 + c)*IMG2 + (size_t)216*IMG + xc;
        #pragma unroll
        for (int q = 0; q < 4; ++q) {
            int r = rh*4 + q;
            int kl1 = r*16 + dx1, kl0 = kl1 + 8;
            float s = 0.f;
            if (v1) s += bf2f(recB[0][pp1][kl1]);
            if (v0) s += bf2f(recB[0][pp0][kl0]);
            op[(size_t)r*IMG] = s * inv;
        }
    }
}

extern "C" void kernel_launch(void* const* d_in, const int* in_sizes, int n_in,
                              void* d_out, int out_size, void* d_ws, size_t ws_size,
                              hipStream_t stream) {
    (void)in_sizes; (void)n_in; (void)out_size; (void)ws_size;
    const float* x     = (const float*)d_in[0];
    const float* W_enc = (const float*)d_in[1];
    const float* b_enc = (const float*)d_in[2];
    const float* W_dec = (const float*)d_in[3];
    const float* b_dec = (const float*)d_in[4];
    float* out = (float*)d_out;

    float*          v   = (float*)d_ws;                          // 768 f32
    unsigned short* APK = (unsigned short*)((char*)d_ws + 4096); // 3 x 65536 bf16 = 384 KB

    pack_M<<<dim3(KK, 3), 256, 0, stream>>>(W_enc, W_dec, b_enc, b_dec, APK, v);
    patch_ae_loop<<<dim3(6, 3, 64), 256, 0, stream>>>(x, APK, v, out);
}

// Round 6
// 51.869 us; speedup vs baseline: 1.4185x; 1.4185x over previous
//
#include <hip/hip_runtime.h>

#define IMG   224
#define IMG2  (IMG*IMG)
#define NN    27          // patches per dim
#define KK    256         // pixels per patch
#define EE    128
#define NSTRIP 28         // output 8-row strips
#define SCOLS 232         // strip row stride in elems (mult of 8 for b128 alignment)
#define RSTR  132         // rec row stride in elems

typedef float f32x4 __attribute__((ext_vector_type(4)));
typedef short s16x8 __attribute__((ext_vector_type(8)));

__device__ __forceinline__ unsigned short f2bf(float f) {
    unsigned int u = __float_as_uint(f);
    u = (u + 0x7fffu + ((u >> 16) & 1u)) >> 16;   // RNE (inputs finite)
    return (unsigned short)u;
}
__device__ __forceinline__ float bf2f(unsigned short u) {
    return __uint_as_float((unsigned int)u << 16);
}
__device__ __forceinline__ uint2 pack4(f32x4 r) {
    unsigned int lo = (unsigned int)f2bf(r.x) | ((unsigned int)f2bf(r.y) << 16);
    unsigned int hi = (unsigned int)f2bf(r.z) | ((unsigned int)f2bf(r.w) << 16);
    return make_uint2(lo, hi);
}

// M[c][k][j] = sum_e W_dec[c][k][e]*W_enc[c][e][j], packed in MFMA A-frag order:
// APK[c][kf(16)][jb(8)][lane(64)][i(8)] = bf16(M[kf*16+(lane&15)][jb*32+8*(lane>>4)+i])
// Also v[c][k] = b_dec[c][k] + sum_e W_dec[c][k][e]*b_enc[c][e].
__global__ void pack_M(const float* __restrict__ W_enc, const float* __restrict__ W_dec,
                       const float* __restrict__ b_enc, const float* __restrict__ b_dec,
                       unsigned short* __restrict__ APK, float* __restrict__ v) {
    int k = blockIdx.x, c = blockIdx.y, j = threadIdx.x;
    const float* wd = W_dec + ((size_t)c*KK + k)*EE;
    const float* we = W_enc + (size_t)c*EE*KK + j;
    float acc = 0.f;
    #pragma unroll 8
    for (int e = 0; e < EE; ++e) acc = fmaf(wd[e], we[(size_t)e*KK], acc);
    int kf = k >> 4, kr = k & 15, jb = j >> 5, g = (j >> 3) & 3, i = j & 7;
    APK[(size_t)c*65536 + (((kf*8 + jb)*64) + g*16 + kr)*8 + i] = f2bf(acc);

    __shared__ float pv[128];
    if (j < EE) pv[j] = wd[j] * b_enc[c*EE + j];
    __syncthreads();
    for (int off = 64; off > 0; off >>= 1) {
        if (j < off) pv[j] += pv[j + off];
        __syncthreads();
    }
    if (j == 0) v[c*KK + k] = pv[0] + b_dec[c*KK + k];
}

__global__ __launch_bounds__(256, 8)
void patch_ae_mfma(const float* __restrict__ x, const unsigned short* __restrict__ APK,
                   const float* __restrict__ v, float* __restrict__ out) {
    // bijective XCD swizzle: 5376 blocks = 8 XCDs x 672; same-XCD neighbors share strip rows
    const int hid = blockIdx.x + NSTRIP*(blockIdx.y + 3*blockIdx.z);
    const int lid = (hid & 7)*672 + (hid >> 3);
    const int s  = lid % NSTRIP;
    const int t2 = lid / NSTRIP;
    const int c  = t2 % 3;
    const int b  = t2 / 3;

    const int tid  = threadIdx.x;
    const int lane = tid & 63, wave = tid >> 6;

    __shared__ __align__(16) unsigned short strip[24*SCOLS];   // 11136 B
    __shared__ __align__(16) unsigned short rec[2][28][RSTR];  // 14784 B (row 27 = garbage dump)
    __shared__ __align__(16) float vsh[256];                   // 1024 B

    vsh[tid] = v[c*256 + tid];

    // wave constants
    const int prow    = wave >> 1;       // 0: ny=s (strip row 8), 1: ny=s-1 (strip row 0)
    const int kq      = wave & 1;
    const int rowbase = prow ? 0 : 8;
    const int kfbase  = prow*8 + kq*4;
    const int g = lane >> 4, lr = lane & 15;
    const s16x8* APKc = (const s16x8*)(APK + (size_t)c*65536);

    // A prefetch for jb=0 — in flight during staging
    s16x8 aNext[4];
    #pragma unroll
    for (int f = 0; f < 4; ++f) aNext[f] = APKc[((kfbase + f)*8 + 0)*64 + lane];

    // ---- stage input strip rows [8s-8, 8s+16), cols [0,224), as bf16 ----
    {
        const float* xb = x + (size_t)(b*3 + c)*IMG2;
        const int ybase = 8*s - 8;
        #pragma unroll
        for (int it = 0; it < 6; ++it) {
            int idx = tid + it*256;
            if (idx < 24*56) {
                int r  = idx / 56, c4 = idx - r*56;
                int yr = ybase + r;
                float4 xv = make_float4(0.f, 0.f, 0.f, 0.f);
                if ((unsigned)yr < IMG)
                    xv = ((const float4*)(xb + (size_t)yr*IMG))[c4];
                f32x4 xr = {xv.x, xv.y, xv.z, xv.w};
                *((uint2*)&strip[r*SCOLS + c4*4]) = pack4(xr);
            }
        }
    }
    __syncthreads();

    // ---- MFMA with 1-deep A pipeline ----
    {
        f32x4 acc[4][2];
        #pragma unroll
        for (int f = 0; f < 4; ++f)
            #pragma unroll
            for (int pf = 0; pf < 2; ++pf)
                acc[f][pf] = (f32x4){0.f, 0.f, 0.f, 0.f};

        // pf1 column: patches 16+lr; lanes lr>=11 (p>=27 unused) clamped in-bounds
        const int c1 = (lr <= 10) ? (128 + 8*lr) : 208;

        #pragma unroll
        for (int jb = 0; jb < 8; ++jb) {
            s16x8 aCur[4];
            #pragma unroll
            for (int f = 0; f < 4; ++f) aCur[f] = aNext[f];
            if (jb < 7) {
                #pragma unroll
                for (int f = 0; f < 4; ++f)
                    aNext[f] = APKc[((kfbase + f)*8 + (jb+1))*64 + lane];
            }
            const int jy  = 2*jb + (g >> 1);
            const int jx0 = (g & 1)*8;
            const unsigned short* srow = &strip[(rowbase + jy)*SCOLS + jx0];
            s16x8 bfrag[2];
            bfrag[0] = *((const s16x8*)&srow[8*lr]);
            bfrag[1] = *((const s16x8*)&srow[c1]);
            __builtin_amdgcn_s_setprio(1);
            #pragma unroll
            for (int f = 0; f < 4; ++f) {
                acc[f][0] = __builtin_amdgcn_mfma_f32_16x16x32_bf16(aCur[f], bfrag[0], acc[f][0], 0, 0, 0);
                acc[f][1] = __builtin_amdgcn_mfma_f32_16x16x32_bf16(aCur[f], bfrag[1], acc[f][1], 0, 0, 0);
            }
            __builtin_amdgcn_s_setprio(0);
        }

        // bias + bf16 store: rec[prow][p][klocal] holds k = prow*128 + klocal
        #pragma unroll
        for (int f = 0; f < 4; ++f) {
            int klocal = kq*64 + f*16 + g*4;
            f32x4 bias = *((const f32x4*)&vsh[prow*128 + klocal]);
            #pragma unroll
            for (int pf = 0; pf < 2; ++pf) {
                f32x4 r = acc[f][pf] + bias;
                int p = min(pf*16 + lr, 27);      // p>=27 -> dump row (never read)
                *((uint2*)&rec[prow][p][klocal]) = pack4(r);
            }
        }
    }
    __syncthreads();

    // ---- combine overlaps, write each pixel once (thread = column, 8 rows) ----
    if (tid < 224) {
        const int xc = tid;
        const int p1 = xc >> 3;
        const int v1 = (p1 <= NN-1);
        const int v0 = (p1 > 0);
        const int p0v = v0 ? p1 - 1 : 0;
        const int dx1 = xc & 7, dx0 = dx1 + 8;
        const int h0 = (s < NSTRIP-1);
        const int h1 = (s > 0);
        const int shift = (v0 & v1) + (h0 & h1);
        const float inv = __int_as_float(0x3f800000 - (shift << 23)); // exact 1/2^shift
        float* orow = out + (size_t)(b*3 + c)*IMG2 + (size_t)(8*s)*IMG + xc;
        #pragma unroll
        for (int ry = 0; ry < 8; ++ry) {
            int kl1 = ry*16 + dx1, kl0 = ry*16 + dx0;
            float sum = 0.f;
            if (v1) {
                if (h0) sum += bf2f(rec[0][p1][kl1]);
                if (h1) sum += bf2f(rec[1][p1][kl1]);
            }
            if (v0) {
                if (h0) sum += bf2f(rec[0][p0v][kl0]);
                if (h1) sum += bf2f(rec[1][p0v][kl0]);
            }
            orow[(size_t)ry*IMG] = sum * inv;
        }
    }
}

extern "C" void kernel_launch(void* const* d_in, const int* in_sizes, int n_in,
                              void* d_out, int out_size, void* d_ws, size_t ws_size,
                              hipStream_t stream) {
    (void)in_sizes; (void)n_in; (void)out_size; (void)ws_size;
    const float* x     = (const float*)d_in[0];
    const float* W_enc = (const float*)d_in[1];
    const float* b_enc = (const float*)d_in[2];
    const float* W_dec = (const float*)d_in[3];
    const float* b_dec = (const float*)d_in[4];
    float* out = (float*)d_out;

    float*          v   = (float*)d_ws;                          // 768 f32
    unsigned short* APK = (unsigned short*)((char*)d_ws + 4096); // 3 x 65536 bf16 = 384 KB

    pack_M<<<dim3(KK, 3), 256, 0, stream>>>(W_enc, W_dec, b_enc, b_dec, APK, v);
    patch_ae_mfma<<<dim3(NSTRIP, 3, 64), 256, 0, stream>>>(x, APK, v, out);
}